// Round 2
// baseline (793.599 us; speedup 1.0000x reference)
//
#include <hip/hip_runtime.h>
#include <math.h>

#define HEADS 8
#define DOUT 64
#define DIN 256
#define HC 512  /* HEADS*DOUT */
#define NEG_SLOPE 0.2f

__device__ __forceinline__ float lrelu(float v) { return v > 0.f ? v : NEG_SLOPE * v; }

// ---------------------------------------------------------------------------
// GEMM: xp[N][512] = x[N][256] @ Wcat[256][512]   (W given as [H][256][64])
// fp32 register-blocked 64x64 tile, 4x4 micro-tile per thread.
// ---------------------------------------------------------------------------
__global__ __launch_bounds__(256) void gemm_kernel(const float* __restrict__ x,
                                                   const float* __restrict__ W,
                                                   float* __restrict__ xp, int N) {
    const int BK = 16;
    __shared__ float As[BK][64 + 4];
    __shared__ float Bs[BK][64 + 4];

    int m0 = blockIdx.x * 64;
    int h = blockIdx.y;  // one head per column tile (BN == DOUT == 64)
    const float* Bsrc = W + (size_t)h * DIN * DOUT;  // [256][64]

    int t = threadIdx.x;
    int c0 = (t & 15) * 4;
    int r0 = (t >> 4) * 4;
    float acc[4][4] = {};

    for (int kt = 0; kt < DIN; kt += BK) {
#pragma unroll
        for (int i = 0; i < 4; i++) {  // A tile: 64 rows x 16 k
            int e = t + 256 * i;
            int row = e >> 4, k = e & 15;
            int gr = m0 + row;
            As[k][row] = (gr < N) ? x[(size_t)gr * DIN + kt + k] : 0.f;
        }
#pragma unroll
        for (int i = 0; i < 4; i++) {  // B tile: 16 k x 64 c (coalesced 64-wide)
            int e = t + 256 * i;
            int k = e >> 6, c = e & 63;
            Bs[k][c] = Bsrc[(size_t)(kt + k) * DOUT + c];
        }
        __syncthreads();
#pragma unroll
        for (int k = 0; k < BK; k++) {
            float a[4], bb[4];
#pragma unroll
            for (int i = 0; i < 4; i++) a[i] = As[k][r0 + i];
#pragma unroll
            for (int j = 0; j < 4; j++) bb[j] = Bs[k][c0 + j];
#pragma unroll
            for (int i = 0; i < 4; i++)
#pragma unroll
                for (int j = 0; j < 4; j++) acc[i][j] += a[i] * bb[j];
        }
        __syncthreads();
    }
#pragma unroll
    for (int i = 0; i < 4; i++) {
        int gr = m0 + r0 + i;
        if (gr < N) {
            float4 v = make_float4(acc[i][0], acc[i][1], acc[i][2], acc[i][3]);
            *(float4*)&xp[(size_t)gr * HC + h * DOUT + c0] = v;
        }
    }
}

// ---------------------------------------------------------------------------
// Per-node attention logits: als[n][h] = xp[n,h,:]·a_src[h]; same for ald.
// ---------------------------------------------------------------------------
__global__ __launch_bounds__(512) void logits_kernel(const float* __restrict__ xp,
                                                     const float* __restrict__ a_src,
                                                     const float* __restrict__ a_dst,
                                                     float* __restrict__ als,
                                                     float* __restrict__ ald) {
    int n = blockIdx.x;
    int tid = threadIdx.x;
    float v = xp[(size_t)n * HC + tid];
    float s1 = v * a_src[tid];
    float s2 = v * a_dst[tid];
#pragma unroll
    for (int d = 32; d > 0; d >>= 1) {
        s1 += __shfl_xor(s1, d);
        s2 += __shfl_xor(s2, d);
    }
    if ((tid & 63) == 0) {
        int h = tid >> 6;
        als[n * HEADS + h] = s1;
        ald[n * HEADS + h] = s2;
    }
}

// ---------------------------------------------------------------------------
// CSR build: degree count -> exclusive scan -> fill
// ---------------------------------------------------------------------------
__global__ void deg_kernel(const int* __restrict__ dst, int* __restrict__ deg, int E) {
    int i = blockIdx.x * blockDim.x + threadIdx.x;
    if (i < E) atomicAdd(&deg[dst[i]], 1);
}

__global__ __launch_bounds__(1024) void scan_kernel(const int* __restrict__ deg,
                                                    int* __restrict__ offs, int N) {
    __shared__ int wsum[16];
    __shared__ int s_carry, s_total;
    int tid = threadIdx.x, wid = tid >> 6, lane = tid & 63;
    if (tid == 0) {
        s_carry = 0;
        offs[0] = 0;
    }
    __syncthreads();
    for (int base = 0; base < N; base += 1024) {
        int i = base + tid;
        int x = (i < N) ? deg[i] : 0;
#pragma unroll
        for (int d = 1; d < 64; d <<= 1) {
            int y = __shfl_up(x, d);
            if (lane >= d) x += y;
        }
        if (lane == 63) wsum[wid] = x;
        __syncthreads();
        if (tid == 0) {
            int run = 0;
#pragma unroll
            for (int w = 0; w < 16; w++) {
                int tv = wsum[w];
                wsum[w] = run;
                run += tv;
            }
            s_total = run;
        }
        __syncthreads();
        int incl = x + wsum[wid] + s_carry;
        if (i < N) offs[i + 1] = incl;
        __syncthreads();
        if (tid == 0) s_carry += s_total;
        __syncthreads();
    }
}

__global__ void fill_kernel(const int* __restrict__ src, const int* __restrict__ dst,
                            const int* __restrict__ offs, int* __restrict__ cursor,
                            int* __restrict__ csr, int E) {
    int i = blockIdx.x * blockDim.x + threadIdx.x;
    if (i < E) {
        int d = dst[i];
        int pos = offs[d] + atomicAdd(&cursor[d], 1);
        csr[pos] = src[i];
    }
}

// ---------------------------------------------------------------------------
// Aggregation: one block per dst node (512 thr = 8 waves = 8 heads),
// lane = output channel.
// ---------------------------------------------------------------------------
__global__ __launch_bounds__(512) void agg_kernel(const float* __restrict__ xp,
                                                  const float* __restrict__ als,
                                                  const float* __restrict__ ald,
                                                  const int* __restrict__ offs,
                                                  const int* __restrict__ csr,
                                                  const float* __restrict__ b,
                                                  float* __restrict__ out, int N) {
    int n = blockIdx.x;
    int tid = threadIdx.x;
    int h = tid >> 6, lane = tid & 63;
    int start = offs[n];
    int deg = offs[n + 1] - start;

    float aldn = ald[n * HEADS + h];
    float e_self = lrelu(als[n * HEADS + h] + aldn);

    // pass 1: segment max (self-loop included)
    float mx = e_self;
    for (int j0 = 0; j0 < deg; j0 += 64) {
        int j = j0 + lane;
        float e = -INFINITY;
        if (j < deg) {
            int s = csr[start + j];
            e = lrelu(als[s * HEADS + h] + aldn);
        }
#pragma unroll
        for (int d = 32; d > 0; d >>= 1) e = fmaxf(e, __shfl_xor(e, d));
        mx = fmaxf(mx, e);
    }

    // pass 2: denom
    float denom = __expf(e_self - mx);
    for (int j0 = 0; j0 < deg; j0 += 64) {
        int j = j0 + lane;
        float ex = 0.f;
        if (j < deg) {
            int s = csr[start + j];
            ex = __expf(lrelu(als[s * HEADS + h] + aldn) - mx);
        }
#pragma unroll
        for (int d = 32; d > 0; d >>= 1) ex += __shfl_xor(ex, d);
        denom += ex;
    }
    float inv = 1.f / denom;

    // pass 3: weighted gather-accumulate; lane = channel
    float acc = __expf(e_self - mx) * inv * xp[(size_t)n * HC + h * DOUT + lane];
    for (int j = 0; j < deg; j++) {
        int s = csr[start + j];  // uniform across wave
        float w = __expf(lrelu(als[s * HEADS + h] + aldn) - mx) * inv;
        acc += w * xp[(size_t)s * HC + h * DOUT + lane];
    }
    out[(size_t)h * N * DOUT + (size_t)n * DOUT + lane] = acc + b[h * DOUT + lane];
}

// ---------------------------------------------------------------------------
extern "C" void kernel_launch(void* const* d_in, const int* in_sizes, int n_in,
                              void* d_out, int out_size, void* d_ws, size_t ws_size,
                              hipStream_t stream) {
    const float* x = (const float*)d_in[0];
    const int* ei = (const int*)d_in[1];
    const float* W = (const float*)d_in[2];
    const float* a_src = (const float*)d_in[3];
    const float* a_dst = (const float*)d_in[4];
    const float* b = (const float*)d_in[5];
    float* out = (float*)d_out;

    int N = in_sizes[0] / DIN;   // 50000
    int E = in_sizes[1] / 2;     // 500000
    const int* src = ei;
    const int* dst = ei + E;

    // workspace layout (~108.3 MB)
    float* xp = (float*)d_ws;                       // N*512 f32
    float* als = xp + (size_t)N * HC;               // N*8
    float* ald = als + (size_t)N * HEADS;           // N*8
    int* deg = (int*)(ald + (size_t)N * HEADS);     // N
    int* offs = deg + N;                            // N+1
    int* cursor = offs + N + 1;                     // N
    int* csr = cursor + N;                          // E

    (void)hipMemsetAsync(deg, 0, (size_t)N * sizeof(int), stream);
    (void)hipMemsetAsync(cursor, 0, (size_t)N * sizeof(int), stream);

    dim3 ggrid((N + 63) / 64, HEADS);
    gemm_kernel<<<ggrid, 256, 0, stream>>>(x, W, xp, N);
    logits_kernel<<<N, 512, 0, stream>>>(xp, a_src, a_dst, als, ald);
    deg_kernel<<<(E + 255) / 256, 256, 0, stream>>>(dst, deg, E);
    scan_kernel<<<1, 1024, 0, stream>>>(deg, offs, N);
    fill_kernel<<<(E + 255) / 256, 256, 0, stream>>>(src, dst, offs, cursor, csr, E);
    agg_kernel<<<N, 512, 0, stream>>>(xp, als, ald, offs, csr, b, out, N);
}

// Round 3
// 500.890 us; speedup vs baseline: 1.5844x; 1.5844x over previous
//
#include <hip/hip_runtime.h>
#include <math.h>

#define HEADS 8
#define DOUT 64
#define DIN 256
#define HC 512  /* HEADS*DOUT */
#define NEG_SLOPE 0.2f

typedef __bf16 bf16x8 __attribute__((ext_vector_type(8)));
typedef float f32x4 __attribute__((ext_vector_type(4)));

__device__ __forceinline__ float lrelu(float v) { return v > 0.f ? v : NEG_SLOPE * v; }

// ---------------------------------------------------------------------------
// W prep: Wt[h][c][k] = bf16(W[h][k][c])   (131072 elements)
// ---------------------------------------------------------------------------
__global__ void wprep_kernel(const float* __restrict__ W, __bf16* __restrict__ Wt) {
    int idx = blockIdx.x * 256 + threadIdx.x;  // enumerates h,k,c
    int h = idx >> 14, rem = idx & 16383, k = rem >> 6, c = rem & 63;
    Wt[(((size_t)h * 64 + c) << 8) + k] = (__bf16)W[idx];
}

// ---------------------------------------------------------------------------
// MFMA GEMM: xp[N][512] = x[N][256] @ W (2 heads per block).
// Block: 256 thr = 4 waves; tile 128 rows x 128 cols; K-chunks of 32.
// A staged fp32->bf16 on the fly; Wt pre-transposed so B frags are contiguous.
// LDS rows padded to 40 bf16 (80 B) -> 2-way bank groups (free).
// ---------------------------------------------------------------------------
__global__ __launch_bounds__(256) void gemm_kernel(const float* __restrict__ x,
                                                   const __bf16* __restrict__ Wt,
                                                   float* __restrict__ xp, int N) {
    __shared__ __bf16 Alds[128 * 40];
    __shared__ __bf16 Blds[128 * 40];

    int m0 = blockIdx.x * 128;
    int colbase = blockIdx.y * 128;  // heads 2y, 2y+1

    int t = threadIdx.x;
    int wv = t >> 6, lane = t & 63, quad = lane >> 4, l16 = lane & 15;
    int k8 = quad * 8;

    f32x4 acc[2][8] = {};

    for (int kt = 0; kt < DIN; kt += 32) {
        // ---- stage A: 128 rows x 32 k, convert fp32->bf16 ----
        {
            int m = t >> 1, half = t & 1;
            int row = m0 + m;
            __bf16 tmp[16];
            if (row < N) {
                const float* sp = x + (size_t)row * DIN + kt + half * 16;
                float4 v0 = *(const float4*)(sp + 0);
                float4 v1 = *(const float4*)(sp + 4);
                float4 v2 = *(const float4*)(sp + 8);
                float4 v3 = *(const float4*)(sp + 12);
                tmp[0] = (__bf16)v0.x; tmp[1] = (__bf16)v0.y; tmp[2] = (__bf16)v0.z; tmp[3] = (__bf16)v0.w;
                tmp[4] = (__bf16)v1.x; tmp[5] = (__bf16)v1.y; tmp[6] = (__bf16)v1.z; tmp[7] = (__bf16)v1.w;
                tmp[8] = (__bf16)v2.x; tmp[9] = (__bf16)v2.y; tmp[10] = (__bf16)v2.z; tmp[11] = (__bf16)v2.w;
                tmp[12] = (__bf16)v3.x; tmp[13] = (__bf16)v3.y; tmp[14] = (__bf16)v3.z; tmp[15] = (__bf16)v3.w;
            } else {
#pragma unroll
                for (int i = 0; i < 16; i++) tmp[i] = (__bf16)0.f;
            }
            *(uint4*)&Alds[m * 40 + half * 16] = *(uint4*)&tmp[0];
            *(uint4*)&Alds[m * 40 + half * 16 + 8] = *(uint4*)&tmp[8];
        }
        // ---- stage B: 128 cols x 32 k (bf16, contiguous along k) ----
#pragma unroll
        for (int i = 0; i < 2; i++) {
            int e = t + 256 * i;
            int c = e >> 2, seg = e & 3;
            const __bf16* sp = Wt + (size_t)(colbase + c) * DIN + kt + seg * 8;
            *(uint4*)&Blds[c * 40 + seg * 8] = *(const uint4*)sp;
        }
        __syncthreads();

        bf16x8 af0 = *(bf16x8*)&Alds[(wv * 32 + l16) * 40 + k8];
        bf16x8 af1 = *(bf16x8*)&Alds[(wv * 32 + 16 + l16) * 40 + k8];
#pragma unroll
        for (int c = 0; c < 8; c++) {
            bf16x8 bf = *(bf16x8*)&Blds[(c * 16 + l16) * 40 + k8];
            acc[0][c] = __builtin_amdgcn_mfma_f32_16x16x32_bf16(af0, bf, acc[0][c], 0, 0, 0);
            acc[1][c] = __builtin_amdgcn_mfma_f32_16x16x32_bf16(af1, bf, acc[1][c], 0, 0, 0);
        }
        __syncthreads();
    }

    // epilogue: D[row=quad*4+r][col=lane&15] per 16x16 tile
#pragma unroll
    for (int s = 0; s < 2; s++) {
        int row0 = m0 + wv * 32 + s * 16 + quad * 4;
#pragma unroll
        for (int c = 0; c < 8; c++) {
            int col = colbase + c * 16 + l16;
#pragma unroll
            for (int r = 0; r < 4; r++) {
                int row = row0 + r;
                if (row < N) xp[(size_t)row * HC + col] = acc[s][c][r];
            }
        }
    }
}

// ---------------------------------------------------------------------------
// Per-node attention logits
// ---------------------------------------------------------------------------
__global__ __launch_bounds__(512) void logits_kernel(const float* __restrict__ xp,
                                                     const float* __restrict__ a_src,
                                                     const float* __restrict__ a_dst,
                                                     float* __restrict__ als,
                                                     float* __restrict__ ald) {
    int n = blockIdx.x;
    int tid = threadIdx.x;
    float v = xp[(size_t)n * HC + tid];
    float s1 = v * a_src[tid];
    float s2 = v * a_dst[tid];
#pragma unroll
    for (int d = 32; d > 0; d >>= 1) {
        s1 += __shfl_xor(s1, d);
        s2 += __shfl_xor(s2, d);
    }
    if ((tid & 63) == 0) {
        int h = tid >> 6;
        als[n * HEADS + h] = s1;
        ald[n * HEADS + h] = s2;
    }
}

// ---------------------------------------------------------------------------
// CSR build
// ---------------------------------------------------------------------------
__global__ void deg_kernel(const int* __restrict__ dst, int* __restrict__ deg, int E) {
    int i = blockIdx.x * blockDim.x + threadIdx.x;
    if (i < E) atomicAdd(&deg[dst[i]], 1);
}

__global__ __launch_bounds__(256) void scan_sums(const int* __restrict__ deg,
                                                 int* __restrict__ bsum, int N) {
    int i = blockIdx.x * 256 + threadIdx.x;
    int v = (i < N) ? deg[i] : 0;
#pragma unroll
    for (int d = 32; d > 0; d >>= 1) v += __shfl_xor(v, d);
    __shared__ int p[4];
    if ((threadIdx.x & 63) == 0) p[threadIdx.x >> 6] = v;
    __syncthreads();
    if (threadIdx.x == 0) bsum[blockIdx.x] = p[0] + p[1] + p[2] + p[3];
}

__global__ __launch_bounds__(256) void scan_boffs(const int* __restrict__ bsum,
                                                  int* __restrict__ boffs, int NB) {
    int t = threadIdx.x, wid = t >> 6, lane = t & 63;
    int orig = (t < NB) ? bsum[t] : 0;
    int v = orig;
#pragma unroll
    for (int d = 1; d < 64; d <<= 1) {
        int y = __shfl_up(v, d);
        if (lane >= d) v += y;
    }
    __shared__ int wt[4];
    if (lane == 63) wt[wid] = v;
    __syncthreads();
    int add = 0;
#pragma unroll
    for (int ww = 0; ww < 4; ww++)
        if (ww < wid) add += wt[ww];
    v += add;
    if (t < NB) boffs[t] = v - orig;  // exclusive
}

__global__ __launch_bounds__(256) void scan_offs(const int* __restrict__ deg,
                                                 const int* __restrict__ boffs,
                                                 int* __restrict__ offs, int N) {
    int b = blockIdx.x, t = threadIdx.x, wid = t >> 6, lane = t & 63;
    int i = b * 256 + t;
    int orig = (i < N) ? deg[i] : 0;
    int v = orig;
#pragma unroll
    for (int d = 1; d < 64; d <<= 1) {
        int y = __shfl_up(v, d);
        if (lane >= d) v += y;
    }
    __shared__ int wt[4];
    if (lane == 63) wt[wid] = v;
    __syncthreads();
    int add = 0;
#pragma unroll
    for (int ww = 0; ww < 4; ww++)
        if (ww < wid) add += wt[ww];
    int incl = v + add;
    int base = boffs[b];
    if (i < N) offs[i] = base + incl - orig;
    if (i == N - 1) offs[N] = base + incl;
}

__global__ void fill_kernel(const int* __restrict__ src, const int* __restrict__ dst,
                            const int* __restrict__ offs, int* __restrict__ cursor,
                            int* __restrict__ csr, int E) {
    int i = blockIdx.x * blockDim.x + threadIdx.x;
    if (i < E) {
        int d = dst[i];
        int pos = offs[d] + atomicAdd(&cursor[d], 1);
        csr[pos] = src[i];
    }
}

// ---------------------------------------------------------------------------
// Aggregation: SINGLE pass. Shift = e_self (softmax shift-invariant; exp args
// bounded ~+-12, fp32-safe). 64 edge weights computed lane-parallel, then
// serial gather uses __shfl so gathers pipeline (4x unroll).
// ---------------------------------------------------------------------------
__global__ __launch_bounds__(512) void agg_kernel(const float* __restrict__ xp,
                                                  const float* __restrict__ als,
                                                  const float* __restrict__ ald,
                                                  const int* __restrict__ offs,
                                                  const int* __restrict__ csr,
                                                  const float* __restrict__ b,
                                                  float* __restrict__ out, int N) {
    int n = blockIdx.x;
    int tid = threadIdx.x;
    int h = tid >> 6, lane = tid & 63;
    int start = offs[n];
    int deg = offs[n + 1] - start;

    float aldn = ald[n * HEADS + h];
    float e_self = lrelu(als[n * HEADS + h] + aldn);

    float denom = 1.f;  // self-loop weight = exp(0)
    float acc = xp[(size_t)n * HC + h * DOUT + lane];

    for (int c0 = 0; c0 < deg; c0 += 64) {
        int j = c0 + lane;
        int s = 0;
        float w = 0.f;
        if (j < deg) {
            s = csr[start + j];
            w = __expf(lrelu(als[s * HEADS + h] + aldn) - e_self);
        }
        int cnt = min(64, deg - c0);
        int jj = 0;
        for (; jj + 4 <= cnt; jj += 4) {
            int s0 = __shfl(s, jj), s1 = __shfl(s, jj + 1), s2 = __shfl(s, jj + 2), s3 = __shfl(s, jj + 3);
            float w0 = __shfl(w, jj), w1 = __shfl(w, jj + 1), w2 = __shfl(w, jj + 2), w3 = __shfl(w, jj + 3);
            float x0 = xp[(size_t)s0 * HC + h * DOUT + lane];
            float x1 = xp[(size_t)s1 * HC + h * DOUT + lane];
            float x2 = xp[(size_t)s2 * HC + h * DOUT + lane];
            float x3 = xp[(size_t)s3 * HC + h * DOUT + lane];
            acc += w0 * x0;
            acc += w1 * x1;
            acc += w2 * x2;
            acc += w3 * x3;
        }
        for (; jj < cnt; jj++) {
            int sj = __shfl(s, jj);
            float wj = __shfl(w, jj);
            acc += wj * xp[(size_t)sj * HC + h * DOUT + lane];
        }
        float ws = w;
#pragma unroll
        for (int d = 32; d > 0; d >>= 1) ws += __shfl_xor(ws, d);
        denom += ws;
    }
    out[(size_t)h * N * DOUT + (size_t)n * DOUT + lane] = acc / denom + b[h * DOUT + lane];
}

// ---------------------------------------------------------------------------
extern "C" void kernel_launch(void* const* d_in, const int* in_sizes, int n_in,
                              void* d_out, int out_size, void* d_ws, size_t ws_size,
                              hipStream_t stream) {
    const float* x = (const float*)d_in[0];
    const int* ei = (const int*)d_in[1];
    const float* W = (const float*)d_in[2];
    const float* a_src = (const float*)d_in[3];
    const float* a_dst = (const float*)d_in[4];
    const float* b = (const float*)d_in[5];
    float* out = (float*)d_out;

    int N = in_sizes[0] / DIN;   // 50000
    int E = in_sizes[1] / 2;     // 500000
    const int* src = ei;
    const int* dst = ei + E;
    int NB = (N + 255) / 256;    // 196

    // workspace layout (~108.6 MB)
    float* xp = (float*)d_ws;                        // N*512 f32
    float* als = xp + (size_t)N * HC;                // N*8
    float* ald = als + (size_t)N * HEADS;            // N*8
    __bf16* Wt = (__bf16*)(ald + (size_t)N * HEADS); // 131072 bf16
    int* deg = (int*)(Wt + HEADS * DIN * DOUT);      // N
    int* offs = deg + N;                             // N+1
    int* cursor = offs + N + 1;                      // N
    int* bsum = cursor + N;                          // NB (<=256)
    int* boffs = bsum + 256;                         // NB
    int* csr = boffs + 256;                          // E

    (void)hipMemsetAsync(deg, 0, (size_t)N * sizeof(int), stream);
    (void)hipMemsetAsync(cursor, 0, (size_t)N * sizeof(int), stream);

    wprep_kernel<<<(HEADS * DIN * DOUT) / 256, 256, 0, stream>>>(W, Wt);
    dim3 ggrid((N + 127) / 128, HEADS / 2);
    gemm_kernel<<<ggrid, 256, 0, stream>>>(x, Wt, xp, N);
    logits_kernel<<<N, 512, 0, stream>>>(xp, a_src, a_dst, als, ald);
    deg_kernel<<<(E + 255) / 256, 256, 0, stream>>>(dst, deg, E);
    scan_sums<<<NB, 256, 0, stream>>>(deg, bsum, N);
    scan_boffs<<<1, 256, 0, stream>>>(bsum, boffs, NB);
    scan_offs<<<NB, 256, 0, stream>>>(deg, boffs, offs, N);
    fill_kernel<<<(E + 255) / 256, 256, 0, stream>>>(src, dst, offs, cursor, csr, E);
    agg_kernel<<<N, 512, 0, stream>>>(xp, als, ald, offs, csr, b, out, N);
}

// Round 4
// 432.857 us; speedup vs baseline: 1.8334x; 1.1572x over previous
//
#include <hip/hip_runtime.h>
#include <math.h>

#define HEADS 8
#define DOUT 64
#define DIN 256
#define HC 512  /* HEADS*DOUT */
#define NEG_SLOPE 0.2f

typedef __bf16 bf16;
typedef __bf16 bf16x8 __attribute__((ext_vector_type(8)));
typedef float f32x4 __attribute__((ext_vector_type(4)));

__device__ __forceinline__ float lrelu(float v) { return v > 0.f ? v : NEG_SLOPE * v; }
__device__ __forceinline__ float bflo(unsigned u) { return __uint_as_float(u << 16); }
__device__ __forceinline__ float bfhi(unsigned u) { return __uint_as_float(u & 0xffff0000u); }

__device__ __forceinline__ void fma8(float* acc, uint4 u, float w) {
    acc[0] += w * bflo(u.x); acc[1] += w * bfhi(u.x);
    acc[2] += w * bflo(u.y); acc[3] += w * bfhi(u.y);
    acc[4] += w * bflo(u.z); acc[5] += w * bfhi(u.z);
    acc[6] += w * bflo(u.w); acc[7] += w * bfhi(u.w);
}

// ---------------------------------------------------------------------------
// W prep: Wt[h][c][k] = bf16(W[h][k][c])
// ---------------------------------------------------------------------------
__global__ void wprep_kernel(const float* __restrict__ W, bf16* __restrict__ Wt) {
    int idx = blockIdx.x * 256 + threadIdx.x;
    int h = idx >> 14, rem = idx & 16383, k = rem >> 6, c = rem & 63;
    Wt[(((size_t)h * 64 + c) << 8) + k] = (bf16)W[idx];
}

// ---------------------------------------------------------------------------
// MFMA GEMM + fused logits. xpb (bf16) = x @ W; als/ald from fp32 acc.
// Block: 256 thr, tile 128 rows x 128 cols (2 heads).
// ---------------------------------------------------------------------------
__global__ __launch_bounds__(256) void gemm_kernel(const float* __restrict__ x,
                                                   const bf16* __restrict__ Wt,
                                                   bf16* __restrict__ xpb,
                                                   const float* __restrict__ a_src,
                                                   const float* __restrict__ a_dst,
                                                   float* __restrict__ als,
                                                   float* __restrict__ ald, int N) {
    __shared__ bf16 Alds[128 * 40];
    __shared__ bf16 Blds[128 * 40];

    int m0 = blockIdx.x * 128;
    int colbase = blockIdx.y * 128;  // heads 2y, 2y+1

    int t = threadIdx.x;
    int wv = t >> 6, lane = t & 63, quad = lane >> 4, l16 = lane & 15;
    int k8 = quad * 8;

    f32x4 acc[2][8] = {};

    for (int kt = 0; kt < DIN; kt += 32) {
        {
            int m = t >> 1, half = t & 1;
            int row = m0 + m;
            bf16 tmp[16];
            if (row < N) {
                const float* sp = x + (size_t)row * DIN + kt + half * 16;
                float4 v0 = *(const float4*)(sp + 0);
                float4 v1 = *(const float4*)(sp + 4);
                float4 v2 = *(const float4*)(sp + 8);
                float4 v3 = *(const float4*)(sp + 12);
                tmp[0] = (bf16)v0.x; tmp[1] = (bf16)v0.y; tmp[2] = (bf16)v0.z; tmp[3] = (bf16)v0.w;
                tmp[4] = (bf16)v1.x; tmp[5] = (bf16)v1.y; tmp[6] = (bf16)v1.z; tmp[7] = (bf16)v1.w;
                tmp[8] = (bf16)v2.x; tmp[9] = (bf16)v2.y; tmp[10] = (bf16)v2.z; tmp[11] = (bf16)v2.w;
                tmp[12] = (bf16)v3.x; tmp[13] = (bf16)v3.y; tmp[14] = (bf16)v3.z; tmp[15] = (bf16)v3.w;
            } else {
#pragma unroll
                for (int i = 0; i < 16; i++) tmp[i] = (bf16)0.f;
            }
            *(uint4*)&Alds[m * 40 + half * 16] = *(uint4*)&tmp[0];
            *(uint4*)&Alds[m * 40 + half * 16 + 8] = *(uint4*)&tmp[8];
        }
#pragma unroll
        for (int i = 0; i < 2; i++) {
            int e = t + 256 * i;
            int c = e >> 2, seg = e & 3;
            const bf16* sp = Wt + (size_t)(colbase + c) * DIN + kt + seg * 8;
            *(uint4*)&Blds[c * 40 + seg * 8] = *(const uint4*)sp;
        }
        __syncthreads();

        bf16x8 af0 = *(bf16x8*)&Alds[(wv * 32 + l16) * 40 + k8];
        bf16x8 af1 = *(bf16x8*)&Alds[(wv * 32 + 16 + l16) * 40 + k8];
#pragma unroll
        for (int c = 0; c < 8; c++) {
            bf16x8 bf = *(bf16x8*)&Blds[(c * 16 + l16) * 40 + k8];
            acc[0][c] = __builtin_amdgcn_mfma_f32_16x16x32_bf16(af0, bf, acc[0][c], 0, 0, 0);
            acc[1][c] = __builtin_amdgcn_mfma_f32_16x16x32_bf16(af1, bf, acc[1][c], 0, 0, 0);
        }
        __syncthreads();
    }

    // ---- epilogue: fused logits + bf16 store ----
    int h0 = colbase >> 6;
    float as8[8], ad8[8];
#pragma unroll
    for (int c = 0; c < 8; c++) {
        as8[c] = a_src[colbase + c * 16 + l16];
        ad8[c] = a_dst[colbase + c * 16 + l16];
    }
#pragma unroll
    for (int s = 0; s < 2; s++) {
        float ls[2][4] = {}, ldd[2][4] = {};
#pragma unroll
        for (int c = 0; c < 8; c++)
#pragma unroll
            for (int r = 0; r < 4; r++) {
                float v = acc[s][c][r];
                ls[c >> 2][r] += v * as8[c];
                ldd[c >> 2][r] += v * ad8[c];
            }
#pragma unroll
        for (int d = 1; d < 16; d <<= 1)
#pragma unroll
            for (int hh = 0; hh < 2; hh++)
#pragma unroll
                for (int r = 0; r < 4; r++) {
                    ls[hh][r] += __shfl_xor(ls[hh][r], d);
                    ldd[hh][r] += __shfl_xor(ldd[hh][r], d);
                }
        if (l16 == 0) {
#pragma unroll
            for (int hh = 0; hh < 2; hh++)
#pragma unroll
                for (int r = 0; r < 4; r++) {
                    int row = m0 + wv * 32 + s * 16 + quad * 4 + r;
                    if (row < N) {
                        als[row * HEADS + h0 + hh] = ls[hh][r];
                        ald[row * HEADS + h0 + hh] = ldd[hh][r];
                    }
                }
        }
#pragma unroll
        for (int c = 0; c < 8; c++)
#pragma unroll
            for (int r = 0; r < 4; r++) {
                int row = m0 + wv * 32 + s * 16 + quad * 4 + r;
                if (row < N) xpb[(size_t)row * HC + colbase + c * 16 + l16] = (bf16)acc[s][c][r];
            }
    }
}

// ---------------------------------------------------------------------------
// CSR build
// ---------------------------------------------------------------------------
__global__ void deg_kernel(const int* __restrict__ dst, int* __restrict__ deg, int E) {
    int i = blockIdx.x * blockDim.x + threadIdx.x;
    if (i < E) atomicAdd(&deg[dst[i]], 1);
}

__global__ __launch_bounds__(256) void scan_sums(const int* __restrict__ deg,
                                                 int* __restrict__ bsum, int N) {
    int i = blockIdx.x * 256 + threadIdx.x;
    int v = (i < N) ? deg[i] : 0;
#pragma unroll
    for (int d = 32; d > 0; d >>= 1) v += __shfl_xor(v, d);
    __shared__ int p[4];
    if ((threadIdx.x & 63) == 0) p[threadIdx.x >> 6] = v;
    __syncthreads();
    if (threadIdx.x == 0) bsum[blockIdx.x] = p[0] + p[1] + p[2] + p[3];
}

__global__ __launch_bounds__(256) void scan_boffs(const int* __restrict__ bsum,
                                                  int* __restrict__ boffs, int NB) {
    int t = threadIdx.x, wid = t >> 6, lane = t & 63;
    int orig = (t < NB) ? bsum[t] : 0;
    int v = orig;
#pragma unroll
    for (int d = 1; d < 64; d <<= 1) {
        int y = __shfl_up(v, d);
        if (lane >= d) v += y;
    }
    __shared__ int wt[4];
    if (lane == 63) wt[wid] = v;
    __syncthreads();
    int add = 0;
#pragma unroll
    for (int ww = 0; ww < 4; ww++)
        if (ww < wid) add += wt[ww];
    v += add;
    if (t < NB) boffs[t] = v - orig;
}

__global__ __launch_bounds__(256) void scan_offs(const int* __restrict__ deg,
                                                 const int* __restrict__ boffs,
                                                 int* __restrict__ offs, int N) {
    int bI = blockIdx.x, t = threadIdx.x, wid = t >> 6, lane = t & 63;
    int i = bI * 256 + t;
    int orig = (i < N) ? deg[i] : 0;
    int v = orig;
#pragma unroll
    for (int d = 1; d < 64; d <<= 1) {
        int y = __shfl_up(v, d);
        if (lane >= d) v += y;
    }
    __shared__ int wt[4];
    if (lane == 63) wt[wid] = v;
    __syncthreads();
    int add = 0;
#pragma unroll
    for (int ww = 0; ww < 4; ww++)
        if (ww < wid) add += wt[ww];
    int incl = v + add;
    int base = boffs[bI];
    if (i < N) offs[i] = base + incl - orig;
    if (i == N - 1) offs[N] = base + incl;
}

__global__ void fill_kernel(const int* __restrict__ src, const int* __restrict__ dst,
                            const int* __restrict__ offs, int* __restrict__ deg,
                            int* __restrict__ csr, int E) {
    int i = blockIdx.x * blockDim.x + threadIdx.x;
    if (i < E) {
        int d = dst[i];
        int pos = offs[d] + atomicSub(&deg[d], 1) - 1;
        csr[pos] = src[i];
    }
}

// ---------------------------------------------------------------------------
// Aggregation: bf16 xp, 8 edges per wave-load (8 lanes x 16B = one 128B
// row-head segment). slot = lane>>3 picks the edge, c8 = lane&7 the columns.
// Single pass, shift = e_self.
// ---------------------------------------------------------------------------
__global__ __launch_bounds__(512) void agg_kernel(const bf16* __restrict__ xp,
                                                  const float* __restrict__ als,
                                                  const float* __restrict__ ald,
                                                  const int* __restrict__ offs,
                                                  const int* __restrict__ csr,
                                                  const float* __restrict__ b,
                                                  float* __restrict__ out, int N) {
    int n = blockIdx.x;
    int tid = threadIdx.x;
    int h = tid >> 6, lane = tid & 63;
    int slot = lane >> 3, c8 = lane & 7;
    int start = offs[n];
    int deg = offs[n + 1] - start;

    float aldn = ald[n * HEADS + h];
    float e_self = lrelu(als[n * HEADS + h] + aldn);

    float denom = 1.f;
    float acc[8] = {};
    if (slot == 0) {
        uint4 u = *(const uint4*)&xp[(unsigned)(n * HC + h * DOUT + c8 * 8)];
        fma8(acc, u, 1.f);
    }

    for (int c0 = 0; c0 < deg; c0 += 64) {
        int j = c0 + lane;
        int s = 0;
        float w = 0.f;
        if (j < deg) {
            s = csr[start + j];
            w = __expf(lrelu(als[s * HEADS + h] + aldn) - e_self);
        }
        int cnt = min(64, deg - c0);
        for (int jj = 0; jj < cnt; jj += 16) {
            int m0e = jj + slot, m1e = m0e + 8;
            int s0 = __shfl(s, m0e), s1 = __shfl(s, m1e);
            float w0 = __shfl(w, m0e), w1 = __shfl(w, m1e);
            if (m0e < cnt) {
                uint4 u = *(const uint4*)&xp[(unsigned)(s0 * HC + h * DOUT + c8 * 8)];
                fma8(acc, u, w0);
            }
            if (m1e < cnt) {
                uint4 u = *(const uint4*)&xp[(unsigned)(s1 * HC + h * DOUT + c8 * 8)];
                fma8(acc, u, w1);
            }
        }
        float ws = w;
#pragma unroll
        for (int d = 32; d > 0; d >>= 1) ws += __shfl_xor(ws, d);
        denom += ws;
    }

#pragma unroll
    for (int d = 8; d <= 32; d <<= 1)
#pragma unroll
        for (int jv = 0; jv < 8; jv++) acc[jv] += __shfl_xor(acc[jv], d);

    float inv = 1.f / denom;
    if (slot == 0) {
        size_t obase = (size_t)h * N * DOUT + (size_t)n * DOUT + c8 * 8;
        int bb = h * DOUT + c8 * 8;
        float4 o0, o1;
        o0.x = acc[0] * inv + b[bb + 0]; o0.y = acc[1] * inv + b[bb + 1];
        o0.z = acc[2] * inv + b[bb + 2]; o0.w = acc[3] * inv + b[bb + 3];
        o1.x = acc[4] * inv + b[bb + 4]; o1.y = acc[5] * inv + b[bb + 5];
        o1.z = acc[6] * inv + b[bb + 6]; o1.w = acc[7] * inv + b[bb + 7];
        *(float4*)&out[obase] = o0;
        *(float4*)&out[obase + 4] = o1;
    }
}

// ---------------------------------------------------------------------------
extern "C" void kernel_launch(void* const* d_in, const int* in_sizes, int n_in,
                              void* d_out, int out_size, void* d_ws, size_t ws_size,
                              hipStream_t stream) {
    const float* x = (const float*)d_in[0];
    const int* ei = (const int*)d_in[1];
    const float* W = (const float*)d_in[2];
    const float* a_src = (const float*)d_in[3];
    const float* a_dst = (const float*)d_in[4];
    const float* b = (const float*)d_in[5];
    float* out = (float*)d_out;

    int N = in_sizes[0] / DIN;   // 50000
    int E = in_sizes[1] / 2;     // 500000
    const int* src = ei;
    const int* dst = ei + E;
    int NB = (N + 255) / 256;    // 196

    // workspace layout (~57 MB)
    bf16* xpb = (bf16*)d_ws;                          // N*512 bf16
    float* als = (float*)(xpb + (size_t)N * HC);      // N*8
    float* ald = als + (size_t)N * HEADS;             // N*8
    bf16* Wt = (bf16*)(ald + (size_t)N * HEADS);      // 131072 bf16
    int* deg = (int*)(Wt + HEADS * DIN * DOUT);       // N
    int* offs = deg + N;                              // N+1
    int* bsum = offs + N + 1;                         // NB (<=256)
    int* boffs = bsum + 256;                          // NB
    int* csr = boffs + 256;                           // E

    (void)hipMemsetAsync(deg, 0, (size_t)N * sizeof(int), stream);

    wprep_kernel<<<(HEADS * DIN * DOUT) / 256, 256, 0, stream>>>(W, Wt);
    dim3 ggrid((N + 127) / 128, HEADS / 2);
    gemm_kernel<<<ggrid, 256, 0, stream>>>(x, Wt, xpb, a_src, a_dst, als, ald, N);
    deg_kernel<<<(E + 255) / 256, 256, 0, stream>>>(dst, deg, E);
    scan_sums<<<NB, 256, 0, stream>>>(deg, bsum, N);
    scan_boffs<<<1, 256, 0, stream>>>(bsum, boffs, NB);
    scan_offs<<<NB, 256, 0, stream>>>(deg, boffs, offs, N);
    fill_kernel<<<(E + 255) / 256, 256, 0, stream>>>(src, dst, offs, deg, csr, E);
    agg_kernel<<<N, 512, 0, stream>>>(xpb, als, ald, offs, csr, b, out, N);
}

// Round 5
// 339.810 us; speedup vs baseline: 2.3354x; 1.2738x over previous
//
#include <hip/hip_runtime.h>
#include <math.h>

#define HEADS 8
#define DOUT 64
#define DIN 256
#define HC 512  /* HEADS*DOUT */
#define NEG_SLOPE 0.2f

typedef __bf16 bf16;
typedef __bf16 bf16x8 __attribute__((ext_vector_type(8)));
typedef float f32x4 __attribute__((ext_vector_type(4)));

__device__ __forceinline__ float lrelu(float v) { return v > 0.f ? v : NEG_SLOPE * v; }
__device__ __forceinline__ float bflo(unsigned u) { return __uint_as_float(u << 16); }
__device__ __forceinline__ float bfhi(unsigned u) { return __uint_as_float(u & 0xffff0000u); }

// acc[0..3] weighted by w0 (head 2hp), acc[4..7] by w1 (head 2hp+1)
__device__ __forceinline__ void fma8x2(float* acc, uint4 u, float w0, float w1) {
    acc[0] += w0 * bflo(u.x); acc[1] += w0 * bfhi(u.x);
    acc[2] += w0 * bflo(u.y); acc[3] += w0 * bfhi(u.y);
    acc[4] += w1 * bflo(u.z); acc[5] += w1 * bfhi(u.z);
    acc[6] += w1 * bflo(u.w); acc[7] += w1 * bfhi(u.w);
}

// ---------------------------------------------------------------------------
// W prep: Wt[h][c][k] = bf16(W[h][k][c])
// ---------------------------------------------------------------------------
__global__ void wprep_kernel(const float* __restrict__ W, bf16* __restrict__ Wt) {
    int idx = blockIdx.x * 256 + threadIdx.x;
    int h = idx >> 14, rem = idx & 16383, k = rem >> 6, c = rem & 63;
    Wt[(((size_t)h * 64 + c) << 8) + k] = (bf16)W[idx];
}

// ---------------------------------------------------------------------------
// MFMA GEMM + fused logits. xpb stored SWIZZLED:
//   elem index = row*512 + hp*128 + l16*8 + c,  actual col = hp*128 + c*16 + l16
// so each thread stores uint4 (8 bf16) and agg reads 16B/lane covering a full
// 1KB node row per wave.
// ---------------------------------------------------------------------------
__global__ __launch_bounds__(256) void gemm_kernel(const float* __restrict__ x,
                                                   const bf16* __restrict__ Wt,
                                                   bf16* __restrict__ xpb,
                                                   const float* __restrict__ a_src,
                                                   const float* __restrict__ a_dst,
                                                   float* __restrict__ als,
                                                   float* __restrict__ ald, int N) {
    __shared__ bf16 Alds[128 * 40];
    __shared__ bf16 Blds[128 * 40];

    int m0 = blockIdx.x * 128;
    int colbase = blockIdx.y * 128;  // heads 2y, 2y+1

    int t = threadIdx.x;
    int wv = t >> 6, lane = t & 63, quad = lane >> 4, l16 = lane & 15;
    int k8 = quad * 8;

    f32x4 acc[2][8] = {};

    for (int kt = 0; kt < DIN; kt += 32) {
        {
            int m = t >> 1, half = t & 1;
            int row = m0 + m;
            bf16 tmp[16];
            if (row < N) {
                const float* sp = x + (size_t)row * DIN + kt + half * 16;
                float4 v0 = *(const float4*)(sp + 0);
                float4 v1 = *(const float4*)(sp + 4);
                float4 v2 = *(const float4*)(sp + 8);
                float4 v3 = *(const float4*)(sp + 12);
                tmp[0] = (bf16)v0.x; tmp[1] = (bf16)v0.y; tmp[2] = (bf16)v0.z; tmp[3] = (bf16)v0.w;
                tmp[4] = (bf16)v1.x; tmp[5] = (bf16)v1.y; tmp[6] = (bf16)v1.z; tmp[7] = (bf16)v1.w;
                tmp[8] = (bf16)v2.x; tmp[9] = (bf16)v2.y; tmp[10] = (bf16)v2.z; tmp[11] = (bf16)v2.w;
                tmp[12] = (bf16)v3.x; tmp[13] = (bf16)v3.y; tmp[14] = (bf16)v3.z; tmp[15] = (bf16)v3.w;
            } else {
#pragma unroll
                for (int i = 0; i < 16; i++) tmp[i] = (bf16)0.f;
            }
            *(uint4*)&Alds[m * 40 + half * 16] = *(uint4*)&tmp[0];
            *(uint4*)&Alds[m * 40 + half * 16 + 8] = *(uint4*)&tmp[8];
        }
#pragma unroll
        for (int i = 0; i < 2; i++) {
            int e = t + 256 * i;
            int c = e >> 2, seg = e & 3;
            const bf16* sp = Wt + (size_t)(colbase + c) * DIN + kt + seg * 8;
            *(uint4*)&Blds[c * 40 + seg * 8] = *(const uint4*)sp;
        }
        __syncthreads();

        bf16x8 af0 = *(bf16x8*)&Alds[(wv * 32 + l16) * 40 + k8];
        bf16x8 af1 = *(bf16x8*)&Alds[(wv * 32 + 16 + l16) * 40 + k8];
#pragma unroll
        for (int c = 0; c < 8; c++) {
            bf16x8 bf = *(bf16x8*)&Blds[(c * 16 + l16) * 40 + k8];
            acc[0][c] = __builtin_amdgcn_mfma_f32_16x16x32_bf16(af0, bf, acc[0][c], 0, 0, 0);
            acc[1][c] = __builtin_amdgcn_mfma_f32_16x16x32_bf16(af1, bf, acc[1][c], 0, 0, 0);
        }
        __syncthreads();
    }

    // ---- epilogue: fused logits (fp32 acc) + swizzled bf16 store ----
    int h0 = colbase >> 6;
    float as8[8], ad8[8];
#pragma unroll
    for (int c = 0; c < 8; c++) {
        as8[c] = a_src[colbase + c * 16 + l16];
        ad8[c] = a_dst[colbase + c * 16 + l16];
    }
#pragma unroll
    for (int s = 0; s < 2; s++) {
        float ls[2][4] = {}, ldd[2][4] = {};
#pragma unroll
        for (int c = 0; c < 8; c++)
#pragma unroll
            for (int r = 0; r < 4; r++) {
                float v = acc[s][c][r];
                ls[c >> 2][r] += v * as8[c];
                ldd[c >> 2][r] += v * ad8[c];
            }
#pragma unroll
        for (int d = 1; d < 16; d <<= 1)
#pragma unroll
            for (int hh = 0; hh < 2; hh++)
#pragma unroll
                for (int r = 0; r < 4; r++) {
                    ls[hh][r] += __shfl_xor(ls[hh][r], d);
                    ldd[hh][r] += __shfl_xor(ldd[hh][r], d);
                }
        if (l16 == 0) {
#pragma unroll
            for (int hh = 0; hh < 2; hh++)
#pragma unroll
                for (int r = 0; r < 4; r++) {
                    int row = m0 + wv * 32 + s * 16 + quad * 4 + r;
                    if (row < N) {
                        als[row * HEADS + h0 + hh] = ls[hh][r];
                        ald[row * HEADS + h0 + hh] = ldd[hh][r];
                    }
                }
        }
        // swizzled store: one uint4 per (s,r)
#pragma unroll
        for (int r = 0; r < 4; r++) {
            int row = m0 + wv * 32 + s * 16 + quad * 4 + r;
            if (row < N) {
                bf16 t8[8];
#pragma unroll
                for (int c = 0; c < 8; c++) t8[c] = (bf16)acc[s][c][r];
                *(uint4*)&xpb[(size_t)row * HC + colbase + l16 * 8] = *(uint4*)t8;
            }
        }
    }
}

// ---------------------------------------------------------------------------
// CSR build
// ---------------------------------------------------------------------------
__global__ void deg_kernel(const int* __restrict__ dst, int* __restrict__ deg, int E) {
    int i = blockIdx.x * blockDim.x + threadIdx.x;
    if (i < E) atomicAdd(&deg[dst[i]], 1);
}

__global__ __launch_bounds__(256) void scan_sums(const int* __restrict__ deg,
                                                 int* __restrict__ bsum, int N) {
    int i = blockIdx.x * 256 + threadIdx.x;
    int v = (i < N) ? deg[i] : 0;
#pragma unroll
    for (int d = 32; d > 0; d >>= 1) v += __shfl_xor(v, d);
    __shared__ int p[4];
    if ((threadIdx.x & 63) == 0) p[threadIdx.x >> 6] = v;
    __syncthreads();
    if (threadIdx.x == 0) bsum[blockIdx.x] = p[0] + p[1] + p[2] + p[3];
}

__global__ __launch_bounds__(256) void scan_boffs(const int* __restrict__ bsum,
                                                  int* __restrict__ boffs, int NB) {
    int t = threadIdx.x, wid = t >> 6, lane = t & 63;
    int orig = (t < NB) ? bsum[t] : 0;
    int v = orig;
#pragma unroll
    for (int d = 1; d < 64; d <<= 1) {
        int y = __shfl_up(v, d);
        if (lane >= d) v += y;
    }
    __shared__ int wt[4];
    if (lane == 63) wt[wid] = v;
    __syncthreads();
    int add = 0;
#pragma unroll
    for (int ww = 0; ww < 4; ww++)
        if (ww < wid) add += wt[ww];
    v += add;
    if (t < NB) boffs[t] = v - orig;
}

__global__ __launch_bounds__(256) void scan_offs(const int* __restrict__ deg,
                                                 const int* __restrict__ boffs,
                                                 int* __restrict__ offs, int N) {
    int bI = blockIdx.x, t = threadIdx.x, wid = t >> 6, lane = t & 63;
    int i = bI * 256 + t;
    int orig = (i < N) ? deg[i] : 0;
    int v = orig;
#pragma unroll
    for (int d = 1; d < 64; d <<= 1) {
        int y = __shfl_up(v, d);
        if (lane >= d) v += y;
    }
    __shared__ int wt[4];
    if (lane == 63) wt[wid] = v;
    __syncthreads();
    int add = 0;
#pragma unroll
    for (int ww = 0; ww < 4; ww++)
        if (ww < wid) add += wt[ww];
    int incl = v + add;
    int base = boffs[bI];
    if (i < N) offs[i] = base + incl - orig;
    if (i == N - 1) offs[N] = base + incl;
}

__global__ void fill_kernel(const int* __restrict__ src, const int* __restrict__ dst,
                            const int* __restrict__ offs, int* __restrict__ deg,
                            int* __restrict__ csr, int E) {
    int i = blockIdx.x * blockDim.x + threadIdx.x;
    if (i < E) {
        int d = dst[i];
        int pos = offs[d] + atomicSub(&deg[d], 1) - 1;
        csr[pos] = src[i];
    }
}

// ---------------------------------------------------------------------------
// Aggregation: ONE WAVE PER DST NODE, all 8 heads. Lane j: hp=j>>4, l16=j&15.
// Lane reads 16B of the swizzled xpb row -> owns cols {c*16+l16} of heads
// 2hp (c=0..3) and 2hp+1 (c=4..7). No cross-lane reduction needed.
// ---------------------------------------------------------------------------
__global__ __launch_bounds__(256) void agg_kernel(const bf16* __restrict__ xp,
                                                  const float* __restrict__ als,
                                                  const float* __restrict__ ald,
                                                  const int* __restrict__ offs,
                                                  const int* __restrict__ csr,
                                                  const float* __restrict__ bias,
                                                  float* __restrict__ out, int N) {
    int n = blockIdx.x * 4 + (threadIdx.x >> 6);
    if (n >= N) return;
    int lane = threadIdx.x & 63;
    int hp = lane >> 4, l16 = lane & 15;

    float2 aldn = *(const float2*)&ald[n * HEADS + hp * 2];
    float2 alsn = *(const float2*)&als[n * HEADS + hp * 2];
    float es0 = lrelu(alsn.x + aldn.x);
    float es1 = lrelu(alsn.y + aldn.y);

    int start = offs[n];
    int deg = offs[n + 1] - start;

    float acc[8];
    {
        uint4 u = *(const uint4*)&xp[(size_t)n * HC + lane * 8];
        acc[0] = bflo(u.x); acc[1] = bfhi(u.x);
        acc[2] = bflo(u.y); acc[3] = bfhi(u.y);
        acc[4] = bflo(u.z); acc[5] = bfhi(u.z);
        acc[6] = bflo(u.w); acc[7] = bfhi(u.w);
    }
    float d0 = 1.f, d1 = 1.f;

    for (int c0 = 0; c0 < deg; c0 += 64) {
        int cnt = min(64, deg - c0);
        int sreg = (lane < cnt) ? csr[start + c0 + lane] : 0;
        int jj = 0;
        for (; jj + 4 <= cnt; jj += 4) {
            int s0 = __shfl(sreg, jj), s1 = __shfl(sreg, jj + 1);
            int s2 = __shfl(sreg, jj + 2), s3 = __shfl(sreg, jj + 3);
            float2 a0 = *(const float2*)&als[s0 * HEADS + hp * 2];
            float2 a1 = *(const float2*)&als[s1 * HEADS + hp * 2];
            float2 a2 = *(const float2*)&als[s2 * HEADS + hp * 2];
            float2 a3 = *(const float2*)&als[s3 * HEADS + hp * 2];
            uint4 u0 = *(const uint4*)&xp[(size_t)s0 * HC + lane * 8];
            uint4 u1 = *(const uint4*)&xp[(size_t)s1 * HC + lane * 8];
            uint4 u2 = *(const uint4*)&xp[(size_t)s2 * HC + lane * 8];
            uint4 u3 = *(const uint4*)&xp[(size_t)s3 * HC + lane * 8];
            float w00 = __expf(lrelu(a0.x + aldn.x) - es0), w01 = __expf(lrelu(a0.y + aldn.y) - es1);
            float w10 = __expf(lrelu(a1.x + aldn.x) - es0), w11 = __expf(lrelu(a1.y + aldn.y) - es1);
            float w20 = __expf(lrelu(a2.x + aldn.x) - es0), w21 = __expf(lrelu(a2.y + aldn.y) - es1);
            float w30 = __expf(lrelu(a3.x + aldn.x) - es0), w31 = __expf(lrelu(a3.y + aldn.y) - es1);
            fma8x2(acc, u0, w00, w01); d0 += w00; d1 += w01;
            fma8x2(acc, u1, w10, w11); d0 += w10; d1 += w11;
            fma8x2(acc, u2, w20, w21); d0 += w20; d1 += w21;
            fma8x2(acc, u3, w30, w31); d0 += w30; d1 += w31;
        }
        for (; jj < cnt; jj++) {
            int s0 = __shfl(sreg, jj);
            float2 a0 = *(const float2*)&als[s0 * HEADS + hp * 2];
            uint4 u0 = *(const uint4*)&xp[(size_t)s0 * HC + lane * 8];
            float w00 = __expf(lrelu(a0.x + aldn.x) - es0), w01 = __expf(lrelu(a0.y + aldn.y) - es1);
            fma8x2(acc, u0, w00, w01); d0 += w00; d1 += w01;
        }
    }

    float i0 = 1.f / d0, i1 = 1.f / d1;
    size_t ob0 = (size_t)(hp * 2) * N * DOUT + (size_t)n * DOUT + l16;
    size_t ob1 = ob0 + (size_t)N * DOUT;
    int bb0 = (hp * 2) * DOUT + l16, bb1 = bb0 + DOUT;
#pragma unroll
    for (int c = 0; c < 4; c++) {
        out[ob0 + c * 16] = acc[c] * i0 + bias[bb0 + c * 16];
        out[ob1 + c * 16] = acc[c + 4] * i1 + bias[bb1 + c * 16];
    }
}

// ---------------------------------------------------------------------------
extern "C" void kernel_launch(void* const* d_in, const int* in_sizes, int n_in,
                              void* d_out, int out_size, void* d_ws, size_t ws_size,
                              hipStream_t stream) {
    const float* x = (const float*)d_in[0];
    const int* ei = (const int*)d_in[1];
    const float* W = (const float*)d_in[2];
    const float* a_src = (const float*)d_in[3];
    const float* a_dst = (const float*)d_in[4];
    const float* b = (const float*)d_in[5];
    float* out = (float*)d_out;

    int N = in_sizes[0] / DIN;   // 50000
    int E = in_sizes[1] / 2;     // 500000
    const int* src = ei;
    const int* dst = ei + E;
    int NB = (N + 255) / 256;    // 196

    // workspace layout (~57 MB)
    bf16* xpb = (bf16*)d_ws;                          // N*512 bf16 (swizzled)
    float* als = (float*)(xpb + (size_t)N * HC);      // N*8
    float* ald = als + (size_t)N * HEADS;             // N*8
    bf16* Wt = (bf16*)(ald + (size_t)N * HEADS);      // 131072 bf16
    int* deg = (int*)(Wt + HEADS * DIN * DOUT);       // N
    int* offs = deg + N;                              // N+1
    int* bsum = offs + N + 1;                         // NB (<=256)
    int* boffs = bsum + 256;                          // NB
    int* csr = boffs + 256;                           // E

    (void)hipMemsetAsync(deg, 0, (size_t)N * sizeof(int), stream);

    wprep_kernel<<<(HEADS * DIN * DOUT) / 256, 256, 0, stream>>>(W, Wt);
    dim3 ggrid((N + 127) / 128, HEADS / 2);
    gemm_kernel<<<ggrid, 256, 0, stream>>>(x, Wt, xpb, a_src, a_dst, als, ald, N);
    deg_kernel<<<(E + 255) / 256, 256, 0, stream>>>(dst, deg, E);
    scan_sums<<<NB, 256, 0, stream>>>(deg, bsum, N);
    scan_boffs<<<1, 256, 0, stream>>>(bsum, boffs, NB);
    scan_offs<<<NB, 256, 0, stream>>>(deg, boffs, offs, N);
    fill_kernel<<<(E + 255) / 256, 256, 0, stream>>>(src, dst, offs, deg, csr, E);
    agg_kernel<<<(N + 3) / 4, 256, 0, stream>>>(xpb, als, ald, offs, csr, b, out, N);
}